// Round 2
// baseline (577.648 us; speedup 1.0000x reference)
//
#include <hip/hip_runtime.h>

#define N_NODES 50000
#define IN_CH   128
#define OUT_CH  64
#define N_EDGES 800000

// NOTE: harness materializes integer inputs as int32 (per spec: "integer ->
// const int*"), even though the reference dtype is int64. Reading as long long
// in round 1 caused OOB -> core dump.

// ---------------- degree / normalization ----------------

__global__ void init_deg(float* __restrict__ deg) {
    int i = blockIdx.x * blockDim.x + threadIdx.x;
    if (i < N_NODES) deg[i] = 1.0f;   // self-loop contributes 1
}

__global__ void accum_deg(const int* __restrict__ col, float* __restrict__ deg) {
    int e = blockIdx.x * blockDim.x + threadIdx.x;
    if (e < N_EDGES) atomicAdd(&deg[col[e]], 1.0f);
}

__global__ void make_dinv(float* __restrict__ deg) {
    int i = blockIdx.x * blockDim.x + threadIdx.x;
    if (i < N_NODES) deg[i] = rsqrtf(deg[i]);  // deg >= 1 always
}

// ---------------- y = x @ W  (128 -> 64 channels) ----------------
// One thread per (node, out_ch). All 64 lanes of a wave share one node:
// x reads are wave-uniform broadcasts, W reads are coalesced 256B lines.

__global__ void xw_gemm(const float* __restrict__ x, const float* __restrict__ W,
                        float* __restrict__ y) {
    int gid = blockIdx.x * blockDim.x + threadIdx.x;
    if (gid >= N_NODES * OUT_CH) return;
    int n = gid >> 6;
    int j = gid & 63;
    const float* xr = x + n * IN_CH;
    float acc = 0.0f;
    #pragma unroll 16
    for (int k = 0; k < IN_CH; ++k) acc += xr[k] * W[k * OUT_CH + j];
    y[gid] = acc;
}

// ---------------- propagation hop ----------------
// Self-loop + init:  h_out[i] = dinv[i]^2 * h_in[i]  (+ bias on last hop)

__global__ void hop_init(const float* __restrict__ hin, const float* __restrict__ dinv,
                         const float* __restrict__ bias, float* __restrict__ hout,
                         int add_bias) {
    int gid = blockIdx.x * blockDim.x + threadIdx.x;
    if (gid >= N_NODES * OUT_CH) return;
    int n = gid >> 6;
    int c = gid & 63;
    float d = dinv[n];
    float v = d * d * hin[gid];
    if (add_bias) v += bias[c];
    hout[gid] = v;
}

// Edge scatter: thread per (edge, channel). Lanes 0..63 of a wave carry one
// edge's 64 channels -> coalesced gather of hin row, coalesced atomics on hout.

__global__ void hop_scatter(const int* __restrict__ row,
                            const int* __restrict__ col,
                            const float* __restrict__ dinv,
                            const float* __restrict__ hin,
                            float* __restrict__ hout) {
    int gid = blockIdx.x * blockDim.x + threadIdx.x;
    if (gid >= N_EDGES * OUT_CH) return;
    int e = gid >> 6;
    int c = gid & 63;
    int s = row[e];   // wave-uniform
    int t = col[e];   // wave-uniform
    float w = dinv[s] * dinv[t];
    atomicAdd(&hout[t * OUT_CH + c], w * hin[s * OUT_CH + c]);
}

// ---------------- launch ----------------

extern "C" void kernel_launch(void* const* d_in, const int* in_sizes, int n_in,
                              void* d_out, int out_size, void* d_ws, size_t ws_size,
                              hipStream_t stream) {
    const float* x  = (const float*)d_in[0];
    const int*   ei = (const int*)d_in[1];   // edge_index [2, E], int32 on device
    const float* W  = (const float*)d_in[2];
    const float* b  = (const float*)d_in[3];
    float*       out = (float*)d_out;

    const int* row = ei;            // sources
    const int* col = ei + N_EDGES;  // targets

    // Workspace: dinv (200KB) + h1 (12.8MB). y lives in d_out (dead before
    // hop 2 overwrites it).
    char* ws = (char*)d_ws;
    float* dinv = (float*)ws;
    size_t off = (size_t)((N_NODES * sizeof(float) + 255) & ~(size_t)255);
    float* h1 = (float*)(ws + off);   // 50000*64 floats

    const int B = 256;
    int gN  = (N_NODES + B - 1) / B;
    int gE  = (N_EDGES + B - 1) / B;
    int gNC = (N_NODES * OUT_CH + B - 1) / B;
    int gEC = (N_EDGES * OUT_CH + B - 1) / B;

    // normalization
    init_deg <<<gN, B, 0, stream>>>(dinv);
    accum_deg<<<gE, B, 0, stream>>>(col, dinv);
    make_dinv<<<gN, B, 0, stream>>>(dinv);

    // channel reduction first (S is linear): y = x @ W   (y := d_out)
    xw_gemm<<<gNC, B, 0, stream>>>(x, W, out);

    // hop 1: h1 = S y      (reads d_out, writes ws)
    hop_init   <<<gNC, B, 0, stream>>>(out, dinv, b, h1, 0);
    hop_scatter<<<gEC, B, 0, stream>>>(row, col, dinv, out, h1);

    // hop 2: out = S h1 + b   (reads ws, writes d_out)
    hop_init   <<<gNC, B, 0, stream>>>(h1, dinv, b, out, 1);
    hop_scatter<<<gEC, B, 0, stream>>>(row, col, dinv, h1, out);
}

// Round 3
// 413.825 us; speedup vs baseline: 1.3959x; 1.3959x over previous
//
#include <hip/hip_runtime.h>

#define N_NODES 50000
#define IN_CH   128
#define OUT_CH  64
#define N_EDGES 800000
#define SCAN_T  1024

// ======================= CSR build (once per launch) =======================

// In-degree histogram over targets (int). dinv derives from this (deg = cnt+1),
// replacing the old float accum_deg.
__global__ void hist_kernel(const int* __restrict__ col, int* __restrict__ cnt) {
    int e = blockIdx.x * blockDim.x + threadIdx.x;
    if (e < N_EDGES) atomicAdd(&cnt[col[e]], 1);
}

__global__ void dinv_kernel(const int* __restrict__ cnt, float* __restrict__ dinv) {
    int i = blockIdx.x * blockDim.x + threadIdx.x;
    if (i < N_NODES) dinv[i] = rsqrtf((float)(cnt[i] + 1));  // +1 self-loop
}

// Exclusive scan of cnt -> ptr. Single workgroup, 1024 threads, chunked:
// thread-local sums -> LDS Hillis-Steele scan -> local prefix writeback.
__global__ void scan_kernel(const int* __restrict__ cnt, int* __restrict__ ptr) {
    __shared__ int partial[SCAN_T];
    const int CH = (N_NODES + SCAN_T - 1) / SCAN_T;  // 49
    int tid = threadIdx.x;
    int base = tid * CH;
    int s = 0;
    for (int i = 0; i < CH; ++i) {
        int idx = base + i;
        if (idx < N_NODES) s += cnt[idx];
    }
    partial[tid] = s;
    __syncthreads();
    for (int off = 1; off < SCAN_T; off <<= 1) {
        int v = (tid >= off) ? partial[tid - off] : 0;
        __syncthreads();
        partial[tid] += v;
        __syncthreads();
    }
    int run = (tid == 0) ? 0 : partial[tid - 1];
    for (int i = 0; i < CH; ++i) {
        int idx = base + i;
        if (idx < N_NODES) { ptr[idx] = run; run += cnt[idx]; }
    }
}

// Bucket edges by target; precompute edge weight dinv[s]*dinv[t] (hop-invariant).
__global__ void scatter_kernel(const int* __restrict__ row, const int* __restrict__ col,
                               const float* __restrict__ dinv, const int* __restrict__ ptr,
                               int* __restrict__ fill, int* __restrict__ esrc,
                               float* __restrict__ ew) {
    int e = blockIdx.x * blockDim.x + threadIdx.x;
    if (e >= N_EDGES) return;
    int s = row[e], t = col[e];
    int pos = ptr[t] + atomicAdd(&fill[t], 1);
    esrc[pos] = s;
    ew[pos]   = dinv[s] * dinv[t];
}

// ======================= y = x @ W (128 -> 64) =======================
// Thread per (node, out_ch); wave shares a node: x broadcast, W coalesced/L1.

__global__ void xw_gemm(const float* __restrict__ x, const float* __restrict__ W,
                        float* __restrict__ y) {
    int gid = blockIdx.x * blockDim.x + threadIdx.x;
    if (gid >= N_NODES * OUT_CH) return;
    int n = gid >> 6;
    int j = gid & 63;
    const float* xr = x + n * IN_CH;
    float acc = 0.0f;
    #pragma unroll 16
    for (int k = 0; k < IN_CH; ++k) acc += xr[k] * W[k * OUT_CH + j];
    y[gid] = acc;
}

// ======================= propagation hop: pull/gather =======================
// One wave per target node; 64 lanes = 64 channels. Sequential loop over
// in-edges: coalesced 256B gathers of hin rows, no atomics, one store/node.
// Self-loop + optional bias folded into the accumulator init.

__global__ void hop_gather(const float* __restrict__ hin, float* __restrict__ hout,
                           const int* __restrict__ ptr, const int* __restrict__ cnt,
                           const int* __restrict__ esrc, const float* __restrict__ ew,
                           const float* __restrict__ dinv, const float* __restrict__ bias,
                           int add_bias) {
    int wid = (blockIdx.x * blockDim.x + threadIdx.x) >> 6;
    int c = threadIdx.x & 63;
    if (wid >= N_NODES) return;
    int t = wid;
    float d = dinv[t];
    float acc = d * d * hin[t * OUT_CH + c];
    if (add_bias) acc += bias[c];
    int e = ptr[t];
    int end = e + cnt[t];
    // unroll x4 for memory-level parallelism on the gathers
    for (; e + 3 < end; e += 4) {
        int s0 = esrc[e], s1 = esrc[e + 1], s2 = esrc[e + 2], s3 = esrc[e + 3];
        float w0 = ew[e], w1 = ew[e + 1], w2 = ew[e + 2], w3 = ew[e + 3];
        float v0 = hin[s0 * OUT_CH + c];
        float v1 = hin[s1 * OUT_CH + c];
        float v2 = hin[s2 * OUT_CH + c];
        float v3 = hin[s3 * OUT_CH + c];
        acc += w0 * v0; acc += w1 * v1; acc += w2 * v2; acc += w3 * v3;
    }
    for (; e < end; ++e) acc += ew[e] * hin[esrc[e] * OUT_CH + c];
    hout[t * OUT_CH + c] = acc;
}

// ======================= launch =======================

extern "C" void kernel_launch(void* const* d_in, const int* in_sizes, int n_in,
                              void* d_out, int out_size, void* d_ws, size_t ws_size,
                              hipStream_t stream) {
    const float* x  = (const float*)d_in[0];
    const int*   ei = (const int*)d_in[1];   // edge_index [2,E], int32 on device
    const float* W  = (const float*)d_in[2];
    const float* b  = (const float*)d_in[3];
    float*       out = (float*)d_out;

    const int* row = ei;            // sources
    const int* col = ei + N_EDGES;  // targets

    // ws layout (~20 MB): cnt | ptr | fill | dinv | esrc | ew | h1
    char* ws = (char*)d_ws;
    size_t a = 0;
    auto alloc = [&](size_t bytes) { char* p = ws + a; a = (a + bytes + 255) & ~(size_t)255; return p; };
    int*   cnt  = (int*)  alloc(N_NODES * sizeof(int));
    int*   ptr  = (int*)  alloc(N_NODES * sizeof(int));
    int*   fill = (int*)  alloc(N_NODES * sizeof(int));
    float* dinv = (float*)alloc(N_NODES * sizeof(float));
    int*   esrc = (int*)  alloc(N_EDGES * sizeof(int));
    float* ew   = (float*)alloc(N_EDGES * sizeof(float));
    float* h1   = (float*)alloc((size_t)N_NODES * OUT_CH * sizeof(float));

    const int B = 256;
    int gE  = (N_EDGES + B - 1) / B;
    int gN  = (N_NODES + B - 1) / B;
    int gNC = (N_NODES * OUT_CH + B - 1) / B;
    int gW  = (N_NODES * (B / 64) - 1 + B) / B;  // wave-per-node grid
    gW = (N_NODES + (B / 64) - 1) / (B / 64);

    hipMemsetAsync(cnt,  0, N_NODES * sizeof(int), stream);
    hipMemsetAsync(fill, 0, N_NODES * sizeof(int), stream);

    // CSR build + normalization
    hist_kernel   <<<gE, B, 0, stream>>>(col, cnt);
    dinv_kernel   <<<gN, B, 0, stream>>>(cnt, dinv);
    scan_kernel   <<<1, SCAN_T, 0, stream>>>(cnt, ptr);
    scatter_kernel<<<gE, B, 0, stream>>>(row, col, dinv, ptr, fill, esrc, ew);

    // y = x @ W  (y := d_out; dead before hop 2 overwrites it)
    xw_gemm<<<gNC, B, 0, stream>>>(x, W, out);

    // hop 1: h1 = S y
    hop_gather<<<gW, B, 0, stream>>>(out, h1, ptr, cnt, esrc, ew, dinv, b, 0);
    // hop 2: out = S h1 + b
    hop_gather<<<gW, B, 0, stream>>>(h1, out, ptr, cnt, esrc, ew, dinv, b, 1);
}

// Round 4
// 247.111 us; speedup vs baseline: 2.3376x; 1.6747x over previous
//
#include <hip/hip_runtime.h>

#define N_NODES 50000
#define IN_CH   128
#define OUT_CH  64
#define N_EDGES 800000
#define NBLK    196   // ceil(N_NODES/256)

// ======================= CSR build (per launch; edges are static but the
// harness re-poisons ws, so rebuild each call) =======================

__global__ void hist_kernel(const int* __restrict__ col, int* __restrict__ cnt) {
    int e = blockIdx.x * blockDim.x + threadIdx.x;
    if (e < N_EDGES) atomicAdd(&cnt[col[e]], 1);
}

// Per-block sum of cnt (coalesced) + dinv = rsqrt(cnt+1) fused in.
__global__ void sum_dinv_kernel(const int* __restrict__ cnt, int* __restrict__ bsum,
                                float* __restrict__ dinv) {
    __shared__ int wsum[4];
    int tid = threadIdx.x;
    int i = blockIdx.x * 256 + tid;
    int v = (i < N_NODES) ? cnt[i] : 0;
    if (i < N_NODES) dinv[i] = rsqrtf((float)(v + 1));  // +1 self-loop
    int s = v;
    #pragma unroll
    for (int off = 32; off > 0; off >>= 1) s += __shfl_down(s, off);
    if ((tid & 63) == 0) wsum[tid >> 6] = s;
    __syncthreads();
    if (tid == 0) bsum[blockIdx.x] = wsum[0] + wsum[1] + wsum[2] + wsum[3];
}

// Exclusive scan of the 196 block sums (single block).
__global__ void scan_bsum_kernel(const int* __restrict__ bsum, int* __restrict__ bpref) {
    __shared__ int sd[256];
    int tid = threadIdx.x;
    int v = (tid < NBLK) ? bsum[tid] : 0;
    sd[tid] = v;
    __syncthreads();
    for (int off = 1; off < 256; off <<= 1) {
        int t = (tid >= off) ? sd[tid - off] : 0;
        __syncthreads();
        sd[tid] += t;
        __syncthreads();
    }
    if (tid < NBLK) bpref[tid] = sd[tid] - v;  // exclusive
}

// Per-block exclusive scan + block prefix -> ptr; fill init fused.
__global__ void scan_final_kernel(const int* __restrict__ cnt, const int* __restrict__ bpref,
                                  int* __restrict__ ptr, int* __restrict__ fill) {
    __shared__ int sd[256];
    int tid = threadIdx.x;
    int i = blockIdx.x * 256 + tid;
    int v = (i < N_NODES) ? cnt[i] : 0;
    sd[tid] = v;
    __syncthreads();
    for (int off = 1; off < 256; off <<= 1) {
        int t = (tid >= off) ? sd[tid - off] : 0;
        __syncthreads();
        sd[tid] += t;
        __syncthreads();
    }
    if (i < N_NODES) {
        ptr[i]  = bpref[blockIdx.x] + sd[tid] - v;  // exclusive
        fill[i] = 0;
    }
}

// Bucket edges by target; pack (src, weight) into one int2.
__global__ void scatter_kernel(const int* __restrict__ row, const int* __restrict__ col,
                               const float* __restrict__ dinv, const int* __restrict__ ptr,
                               int* __restrict__ fill, int2* __restrict__ esw) {
    int e = blockIdx.x * blockDim.x + threadIdx.x;
    if (e >= N_EDGES) return;
    int s = row[e], t = col[e];
    int pos = ptr[t] + atomicAdd(&fill[t], 1);
    esw[pos] = make_int2(s, __float_as_int(dinv[s] * dinv[t]));
}

// ======================= y = x @ W (128 -> 64) =======================
// Wave handles 4 nodes; node base forced uniform (readfirstlane) so x-row
// loads compile to scalar loads (s_load), freeing the vector pipe. W[k][c]
// reads are coalesced 256B, L1-resident (32KB), amortized over 4 nodes.

__global__ __launch_bounds__(256) void xw_gemm(const float* __restrict__ x,
                                               const float* __restrict__ W,
                                               float* __restrict__ y) {
    int lane = threadIdx.x & 63;
    int n0 = __builtin_amdgcn_readfirstlane((blockIdx.x * 4 + (threadIdx.x >> 6)) * 4);
    const float* x0 = x + (size_t)n0 * IN_CH;   // 4 consecutive rows
    const float* wc = W + lane;
    float acc0 = 0.f, acc1 = 0.f, acc2 = 0.f, acc3 = 0.f;
    #pragma unroll 4
    for (int k = 0; k < IN_CH; k += 2) {
        float w0 = wc[k * OUT_CH];
        float w1 = wc[(k + 1) * OUT_CH];
        acc0 += x0[k]       * w0 + x0[k + 1]       * w1;
        acc1 += x0[128 + k] * w0 + x0[129 + k]     * w1;
        acc2 += x0[256 + k] * w0 + x0[257 + k]     * w1;
        acc3 += x0[384 + k] * w0 + x0[385 + k]     * w1;
    }
    int o = n0 * OUT_CH + lane;
    y[o]       = acc0;
    y[o + 64]  = acc1;
    y[o + 128] = acc2;
    y[o + 192] = acc3;
}

// ======================= propagation hop: pull/gather =======================
// Wave per target node (uniform t -> ptr/cnt/dinv are s_loads). Edge metadata
// loaded lane-parallel (coalesced int2) then broadcast per edge via readlane:
// src/weight land in SGPRs, gather address = SGPR base + lane*4, no atomics.

__global__ __launch_bounds__(256) void hop_gather(const float* __restrict__ hin,
        float* __restrict__ hout, const int* __restrict__ ptr, const int* __restrict__ cnt,
        const int2* __restrict__ esw, const float* __restrict__ dinv,
        const float* __restrict__ bias, int add_bias) {
    int lane = threadIdx.x & 63;
    int t = __builtin_amdgcn_readfirstlane(blockIdx.x * 4 + (threadIdx.x >> 6));
    if (t >= N_NODES) return;
    int e0  = ptr[t];
    int deg = cnt[t];
    float d = dinv[t];
    float acc = d * d * hin[t * OUT_CH + lane];   // self-loop term
    if (add_bias) acc += bias[lane];

    for (int base = 0; base < deg; base += 64) {
        int m = deg - base;
        if (m > 64) m = 64;
        int2 p = make_int2(0, 0);
        if (lane < m) p = esw[e0 + base + lane];
        int i = 0;
        for (; i + 4 <= m; i += 4) {
            int   s0 = __builtin_amdgcn_readlane(p.x, i);
            int   s1 = __builtin_amdgcn_readlane(p.x, i + 1);
            int   s2 = __builtin_amdgcn_readlane(p.x, i + 2);
            int   s3 = __builtin_amdgcn_readlane(p.x, i + 3);
            float w0 = __int_as_float(__builtin_amdgcn_readlane(p.y, i));
            float w1 = __int_as_float(__builtin_amdgcn_readlane(p.y, i + 1));
            float w2 = __int_as_float(__builtin_amdgcn_readlane(p.y, i + 2));
            float w3 = __int_as_float(__builtin_amdgcn_readlane(p.y, i + 3));
            float v0 = hin[s0 * OUT_CH + lane];
            float v1 = hin[s1 * OUT_CH + lane];
            float v2 = hin[s2 * OUT_CH + lane];
            float v3 = hin[s3 * OUT_CH + lane];
            acc += w0 * v0;
            acc += w1 * v1;
            acc += w2 * v2;
            acc += w3 * v3;
        }
        for (; i < m; ++i) {
            int   s = __builtin_amdgcn_readlane(p.x, i);
            float w = __int_as_float(__builtin_amdgcn_readlane(p.y, i));
            acc += w * hin[s * OUT_CH + lane];
        }
    }
    hout[t * OUT_CH + lane] = acc;
}

// ======================= launch =======================

extern "C" void kernel_launch(void* const* d_in, const int* in_sizes, int n_in,
                              void* d_out, int out_size, void* d_ws, size_t ws_size,
                              hipStream_t stream) {
    const float* x  = (const float*)d_in[0];
    const int*   ei = (const int*)d_in[1];   // edge_index [2,E], int32 on device
    const float* W  = (const float*)d_in[2];
    const float* b  = (const float*)d_in[3];
    float*       out = (float*)d_out;

    const int* row = ei;            // sources
    const int* col = ei + N_EDGES;  // targets

    // ws (~20 MB): cnt | ptr | fill | dinv | bsum | bpref | esw | h1
    char* ws = (char*)d_ws;
    size_t a = 0;
    auto alloc = [&](size_t bytes) { char* p = ws + a; a = (a + bytes + 255) & ~(size_t)255; return p; };
    int*   cnt   = (int*)  alloc(N_NODES * sizeof(int));
    int*   ptr   = (int*)  alloc(N_NODES * sizeof(int));
    int*   fill  = (int*)  alloc(N_NODES * sizeof(int));
    float* dinv  = (float*)alloc(N_NODES * sizeof(float));
    int*   bsum  = (int*)  alloc(NBLK * sizeof(int));
    int*   bpref = (int*)  alloc(NBLK * sizeof(int));
    int2*  esw   = (int2*) alloc((size_t)N_EDGES * sizeof(int2));
    float* h1    = (float*)alloc((size_t)N_NODES * OUT_CH * sizeof(float));

    const int B = 256;
    int gE = (N_EDGES + B - 1) / B;          // 3125
    int gG = (N_NODES * 4 + B - 1) / B;      // xw_gemm: wave=4 nodes -> 3125
    gG = (N_NODES + 15) / 16;
    int gH = (N_NODES + 3) / 4;              // hop: wave=1 node, 4 waves/block

    hipMemsetAsync(cnt, 0, N_NODES * sizeof(int), stream);

    // CSR build + normalization
    hist_kernel      <<<gE, B, 0, stream>>>(col, cnt);
    sum_dinv_kernel  <<<NBLK, B, 0, stream>>>(cnt, bsum, dinv);
    scan_bsum_kernel <<<1, B, 0, stream>>>(bsum, bpref);
    scan_final_kernel<<<NBLK, B, 0, stream>>>(cnt, bpref, ptr, fill);
    scatter_kernel   <<<gE, B, 0, stream>>>(row, col, dinv, ptr, fill, esw);

    // y = x @ W  (y := d_out; dead before hop 2 overwrites it)
    xw_gemm<<<gG, B, 0, stream>>>(x, W, out);

    // hop 1: h1 = S y
    hop_gather<<<gH, B, 0, stream>>>(out, h1, ptr, cnt, esw, dinv, b, 0);
    // hop 2: out = S h1 + b
    hop_gather<<<gH, B, 0, stream>>>(h1, out, ptr, cnt, esw, dinv, b, 1);
}

// Round 5
// 246.124 us; speedup vs baseline: 2.3470x; 1.0040x over previous
//
#include <hip/hip_runtime.h>

#define N_NODES 50000
#define IN_CH   128
#define OUT_CH  64
#define N_EDGES 800000
#define NBLK    196   // ceil(N_NODES/256)

// ======================= CSR build (per launch; ws is re-poisoned every call
// so the CSR must be rebuilt) =======================

__global__ void hist_kernel(const int* __restrict__ col, int* __restrict__ cnt) {
    int e = blockIdx.x * blockDim.x + threadIdx.x;
    if (e < N_EDGES) atomicAdd(&cnt[col[e]], 1);
}

// Per-block sum of cnt (coalesced) + dinv = rsqrt(cnt+1) fused in.
__global__ void sum_dinv_kernel(const int* __restrict__ cnt, int* __restrict__ bsum,
                                float* __restrict__ dinv) {
    __shared__ int wsum[4];
    int tid = threadIdx.x;
    int i = blockIdx.x * 256 + tid;
    int v = (i < N_NODES) ? cnt[i] : 0;
    if (i < N_NODES) dinv[i] = rsqrtf((float)(v + 1));  // +1 self-loop
    int s = v;
    #pragma unroll
    for (int off = 32; off > 0; off >>= 1) s += __shfl_down(s, off);
    if ((tid & 63) == 0) wsum[tid >> 6] = s;
    __syncthreads();
    if (tid == 0) bsum[blockIdx.x] = wsum[0] + wsum[1] + wsum[2] + wsum[3];
}

// Exclusive scan of the 196 block sums (single block).
__global__ void scan_bsum_kernel(const int* __restrict__ bsum, int* __restrict__ bpref) {
    __shared__ int sd[256];
    int tid = threadIdx.x;
    int v = (tid < NBLK) ? bsum[tid] : 0;
    sd[tid] = v;
    __syncthreads();
    for (int off = 1; off < 256; off <<= 1) {
        int t = (tid >= off) ? sd[tid - off] : 0;
        __syncthreads();
        sd[tid] += t;
        __syncthreads();
    }
    if (tid < NBLK) bpref[tid] = sd[tid] - v;  // exclusive
}

// Per-block exclusive scan + block prefix -> ptr; fill init fused.
__global__ void scan_final_kernel(const int* __restrict__ cnt, const int* __restrict__ bpref,
                                  int* __restrict__ ptr, int* __restrict__ fill) {
    __shared__ int sd[256];
    int tid = threadIdx.x;
    int i = blockIdx.x * 256 + tid;
    int v = (i < N_NODES) ? cnt[i] : 0;
    sd[tid] = v;
    __syncthreads();
    for (int off = 1; off < 256; off <<= 1) {
        int t = (tid >= off) ? sd[tid - off] : 0;
        __syncthreads();
        sd[tid] += t;
        __syncthreads();
    }
    if (i < N_NODES) {
        ptr[i]  = bpref[blockIdx.x] + sd[tid] - v;  // exclusive
        fill[i] = 0;
    }
}

// Bucket edges by target; pack (src, weight) into one int2.
__global__ void scatter_kernel(const int* __restrict__ row, const int* __restrict__ col,
                               const float* __restrict__ dinv, const int* __restrict__ ptr,
                               int* __restrict__ fill, int2* __restrict__ esw) {
    int e = blockIdx.x * blockDim.x + threadIdx.x;
    if (e >= N_EDGES) return;
    int s = row[e], t = col[e];
    int pos = ptr[t] + atomicAdd(&fill[t], 1);
    esw[pos] = make_int2(s, __float_as_int(dinv[s] * dinv[t]));
}

// ======================= y = x @ W (128 -> 64) =======================
// Wave handles 4 nodes; node base forced uniform (readfirstlane) so x-row
// loads compile to scalar loads, freeing the vector pipe. W[k][c] reads are
// coalesced 256B, L1-resident, amortized over 4 nodes. (~measured-good in R4)

__global__ __launch_bounds__(256) void xw_gemm(const float* __restrict__ x,
                                               const float* __restrict__ W,
                                               float* __restrict__ y) {
    int lane = threadIdx.x & 63;
    int n0 = __builtin_amdgcn_readfirstlane((blockIdx.x * 4 + (threadIdx.x >> 6)) * 4);
    const float* x0 = x + (size_t)n0 * IN_CH;   // 4 consecutive rows
    const float* wc = W + lane;
    float acc0 = 0.f, acc1 = 0.f, acc2 = 0.f, acc3 = 0.f;
    #pragma unroll 4
    for (int k = 0; k < IN_CH; k += 2) {
        float w0 = wc[k * OUT_CH];
        float w1 = wc[(k + 1) * OUT_CH];
        acc0 += x0[k]       * w0 + x0[k + 1]   * w1;
        acc1 += x0[128 + k] * w0 + x0[129 + k] * w1;
        acc2 += x0[256 + k] * w0 + x0[257 + k] * w1;
        acc3 += x0[384 + k] * w0 + x0[385 + k] * w1;
    }
    int o = n0 * OUT_CH + lane;
    y[o]       = acc0;
    y[o + 64]  = acc1;
    y[o + 128] = acc2;
    y[o + 192] = acc3;
}

// ======================= propagation hop: pull/gather v3 =======================
// Wave per target node. Wave split into 4 groups of 16 lanes: group g handles
// edge base+g; lane carries channels q*4..q*4+3 as float4. One dwordx4 gather
// fetches 4 edges' rows (1KB/instr, 16B/lane) -- 4x fewer gather instructions
// than one-row-per-instruction. Edge meta = one int2 load per group (L1
// broadcast across the 16 lanes). Unroll x2 -> 8 edges in flight. Cross-group
// reduce via shfl_xor(16/32); group 0 stores float4 (coalesced 256B row).

__global__ __launch_bounds__(256) void hop_gather(const float4* __restrict__ hin4,
        float4* __restrict__ hout4, const int* __restrict__ ptr, const int* __restrict__ cnt,
        const int2* __restrict__ esw, const float* __restrict__ dinv,
        const float4* __restrict__ bias4, int add_bias) {
    int lane = threadIdx.x & 63;
    int g = lane >> 4;    // edge slot 0..3
    int q = lane & 15;    // channel quad: channels q*4..q*4+3
    int t = __builtin_amdgcn_readfirstlane(blockIdx.x * 4 + (threadIdx.x >> 6));
    if (t >= N_NODES) return;
    int e0  = ptr[t];
    int deg = cnt[t];
    float d = dinv[t];

    float4 acc = make_float4(0.f, 0.f, 0.f, 0.f);
    if (g == 0) {                       // self-loop + bias only once
        float4 sv = hin4[t * 16 + q];
        float dd = d * d;
        acc.x = dd * sv.x; acc.y = dd * sv.y; acc.z = dd * sv.z; acc.w = dd * sv.w;
        if (add_bias) {
            float4 bv = bias4[q];
            acc.x += bv.x; acc.y += bv.y; acc.z += bv.z; acc.w += bv.w;
        }
    }

    int base = 0;
    for (; base + 8 <= deg; base += 8) {   // 8 edges per iter, 2 gathers in flight
        int2 pA = esw[e0 + base + g];
        int2 pB = esw[e0 + base + 4 + g];
        float4 vA = hin4[pA.x * 16 + q];
        float4 vB = hin4[pB.x * 16 + q];
        float wA = __int_as_float(pA.y);
        float wB = __int_as_float(pB.y);
        acc.x += wA * vA.x; acc.y += wA * vA.y; acc.z += wA * vA.z; acc.w += wA * vA.w;
        acc.x += wB * vB.x; acc.y += wB * vB.y; acc.z += wB * vB.z; acc.w += wB * vB.w;
    }
    for (; base < deg; base += 4) {        // predicated tail (up to 2 iters)
        float4 v = make_float4(0.f, 0.f, 0.f, 0.f);
        float w = 0.f;
        if (base + g < deg) {
            int2 p = esw[e0 + base + g];
            w = __int_as_float(p.y);
            v = hin4[p.x * 16 + q];
        }
        acc.x += w * v.x; acc.y += w * v.y; acc.z += w * v.z; acc.w += w * v.w;
    }

    // reduce across the 4 edge groups (lanes q, q+16, q+32, q+48)
    acc.x += __shfl_xor(acc.x, 16); acc.y += __shfl_xor(acc.y, 16);
    acc.z += __shfl_xor(acc.z, 16); acc.w += __shfl_xor(acc.w, 16);
    acc.x += __shfl_xor(acc.x, 32); acc.y += __shfl_xor(acc.y, 32);
    acc.z += __shfl_xor(acc.z, 32); acc.w += __shfl_xor(acc.w, 32);

    if (g == 0) hout4[t * 16 + q] = acc;   // 16 lanes x 16B = 256B row store
}

// ======================= launch =======================

extern "C" void kernel_launch(void* const* d_in, const int* in_sizes, int n_in,
                              void* d_out, int out_size, void* d_ws, size_t ws_size,
                              hipStream_t stream) {
    const float* x  = (const float*)d_in[0];
    const int*   ei = (const int*)d_in[1];   // edge_index [2,E], int32 on device
    const float* W  = (const float*)d_in[2];
    const float* b  = (const float*)d_in[3];
    float*       out = (float*)d_out;

    const int* row = ei;            // sources
    const int* col = ei + N_EDGES;  // targets

    // ws (~20 MB): cnt | ptr | fill | dinv | bsum | bpref | esw | h1
    char* ws = (char*)d_ws;
    size_t a = 0;
    auto alloc = [&](size_t bytes) { char* p = ws + a; a = (a + bytes + 255) & ~(size_t)255; return p; };
    int*   cnt   = (int*)  alloc(N_NODES * sizeof(int));
    int*   ptr   = (int*)  alloc(N_NODES * sizeof(int));
    int*   fill  = (int*)  alloc(N_NODES * sizeof(int));
    float* dinv  = (float*)alloc(N_NODES * sizeof(float));
    int*   bsum  = (int*)  alloc(NBLK * sizeof(int));
    int*   bpref = (int*)  alloc(NBLK * sizeof(int));
    int2*  esw   = (int2*) alloc((size_t)N_EDGES * sizeof(int2));
    float* h1    = (float*)alloc((size_t)N_NODES * OUT_CH * sizeof(float));

    const int B = 256;
    int gE = (N_EDGES + B - 1) / B;   // 3125
    int gG = (N_NODES + 15) / 16;     // gemm: wave=4 nodes, 4 waves/block
    int gH = (N_NODES + 3) / 4;       // hop: wave=1 node, 4 waves/block

    hipMemsetAsync(cnt, 0, N_NODES * sizeof(int), stream);

    // CSR build + normalization
    hist_kernel      <<<gE, B, 0, stream>>>(col, cnt);
    sum_dinv_kernel  <<<NBLK, B, 0, stream>>>(cnt, bsum, dinv);
    scan_bsum_kernel <<<1, B, 0, stream>>>(bsum, bpref);
    scan_final_kernel<<<NBLK, B, 0, stream>>>(cnt, bpref, ptr, fill);
    scatter_kernel   <<<gE, B, 0, stream>>>(row, col, dinv, ptr, fill, esw);

    // y = x @ W  (y := d_out; dead before hop 2 overwrites it)
    xw_gemm<<<gG, B, 0, stream>>>(x, W, out);

    // hop 1: h1 = S y
    hop_gather<<<gH, B, 0, stream>>>((const float4*)out, (float4*)h1, ptr, cnt, esw,
                                     dinv, (const float4*)b, 0);
    // hop 2: out = S h1 + b
    hop_gather<<<gH, B, 0, stream>>>((const float4*)h1, (float4*)out, ptr, cnt, esw,
                                     dinv, (const float4*)b, 1);
}